// Round 7
// baseline (94.334 us; speedup 1.0000x reference)
//
#include <hip/hip_runtime.h>

#define EPSV   1e-6f
#define SMOOTH 0.025f
#define HALF   4096      // chunk0 = [0,4096), chunk1 = [4096,T)
#define WARM   512       // EMA warm-up steps for chunk1 (a^512 ~ 2.4e-6)

typedef float v4f __attribute__((ext_vector_type(4)));

__device__ __forceinline__ float fast_log2(float v) { return __builtin_amdgcn_logf(v); }
__device__ __forceinline__ float fast_exp2(float v) { return __builtin_amdgcn_exp2f(v); }

struct KC {
    float a1, a2, a3, a4;            // a^k
    float e0, e1, e2, e3, e4, e5;    // a^(4*2^s)
    float a4lane;                    // a^(4*lane)
    float a256;                      // a^256
    int   lane;
};

#define KS_STEP(P, d, e) \
    u = __shfl_up(P, d, 64); P = fmaf(c.lane >= d ? e : 0.f, u, P);

// 4 interleaved Kogge-Stone chains over 4 coalesced 256-elem tiles
// (lane owns tile_k[4l..4l+3]). Same shuffle count per element as the
// 2-tile version but 4-way ILP through the 6-step dependent shuffle
// phase; inter-tile carry enters via 4 trailing FMAs only.
__device__ __forceinline__ void scan4(const KC& c,
        const float x0[4], const float x1[4], const float x2[4], const float x3[4],
        float& m0, float M0[4], float M1[4], float M2[4], float M3[4]) {
    const float b = SMOOTH;
    float q00 = b * x0[0];
    float q01 = fmaf(c.a1, q00, b * x0[1]);
    float q02 = fmaf(c.a1, q01, b * x0[2]);
    float q03 = fmaf(c.a1, q02, b * x0[3]);
    float q10 = b * x1[0];
    float q11 = fmaf(c.a1, q10, b * x1[1]);
    float q12 = fmaf(c.a1, q11, b * x1[2]);
    float q13 = fmaf(c.a1, q12, b * x1[3]);
    float q20 = b * x2[0];
    float q21 = fmaf(c.a1, q20, b * x2[1]);
    float q22 = fmaf(c.a1, q21, b * x2[2]);
    float q23 = fmaf(c.a1, q22, b * x2[3]);
    float q30 = b * x3[0];
    float q31 = fmaf(c.a1, q30, b * x3[1]);
    float q32 = fmaf(c.a1, q31, b * x3[2]);
    float q33 = fmaf(c.a1, q32, b * x3[3]);

    float P0 = q03, P1 = q13, P2 = q23, P3 = q33, u;
    KS_STEP(P0, 1,  c.e0) KS_STEP(P1, 1,  c.e0) KS_STEP(P2, 1,  c.e0) KS_STEP(P3, 1,  c.e0)
    KS_STEP(P0, 2,  c.e1) KS_STEP(P1, 2,  c.e1) KS_STEP(P2, 2,  c.e1) KS_STEP(P3, 2,  c.e1)
    KS_STEP(P0, 4,  c.e2) KS_STEP(P1, 4,  c.e2) KS_STEP(P2, 4,  c.e2) KS_STEP(P3, 4,  c.e2)
    KS_STEP(P0, 8,  c.e3) KS_STEP(P1, 8,  c.e3) KS_STEP(P2, 8,  c.e3) KS_STEP(P3, 8,  c.e3)
    KS_STEP(P0, 16, c.e4) KS_STEP(P1, 16, c.e4) KS_STEP(P2, 16, c.e4) KS_STEP(P3, 16, c.e4)
    KS_STEP(P0, 32, c.e5) KS_STEP(P1, 32, c.e5) KS_STEP(P2, 32, c.e5) KS_STEP(P3, 32, c.e5)

    float T0 = __shfl(P0, 63, 64);
    float T1 = __shfl(P1, 63, 64);
    float T2 = __shfl(P2, 63, 64);
    float T3 = __shfl(P3, 63, 64);
    float E0 = __shfl_up(P0, 1, 64); if (c.lane == 0) E0 = 0.f;
    float E1 = __shfl_up(P1, 1, 64); if (c.lane == 0) E1 = 0.f;
    float E2 = __shfl_up(P2, 1, 64); if (c.lane == 0) E2 = 0.f;
    float E3 = __shfl_up(P3, 1, 64); if (c.lane == 0) E3 = 0.f;

    float mA = m0;                       // state entering tile 0
    float mB = fmaf(c.a256, mA, T0);
    float mC = fmaf(c.a256, mB, T1);
    float mD = fmaf(c.a256, mC, T2);
    m0       = fmaf(c.a256, mD, T3);     // carry out

    float s0 = fmaf(c.a4lane, mA, E0);
    float s1 = fmaf(c.a4lane, mB, E1);
    float s2 = fmaf(c.a4lane, mC, E2);
    float s3 = fmaf(c.a4lane, mD, E3);
    M0[0] = fmaf(c.a1, s0, q00); M0[1] = fmaf(c.a2, s0, q01);
    M0[2] = fmaf(c.a3, s0, q02); M0[3] = fmaf(c.a4, s0, q03);
    M1[0] = fmaf(c.a1, s1, q10); M1[1] = fmaf(c.a2, s1, q11);
    M1[2] = fmaf(c.a3, s1, q12); M1[3] = fmaf(c.a4, s1, q13);
    M2[0] = fmaf(c.a1, s2, q20); M2[1] = fmaf(c.a2, s2, q21);
    M2[2] = fmaf(c.a3, s2, q22); M2[3] = fmaf(c.a4, s2, q23);
    M3[0] = fmaf(c.a1, s3, q30); M3[1] = fmaf(c.a2, s3, q31);
    M3[2] = fmaf(c.a3, s3, q32); M3[3] = fmaf(c.a4, s3, q33);
}

// 2-tile variant (warm-up only)
__device__ __forceinline__ void scan2(const KC& c,
        const float xa[4], const float xb[4], float& m0) {
    const float b = SMOOTH;
    float qa0 = b * xa[0];
    float qa1 = fmaf(c.a1, qa0, b * xa[1]);
    float qa2 = fmaf(c.a1, qa1, b * xa[2]);
    float qa3 = fmaf(c.a1, qa2, b * xa[3]);
    float qb0 = b * xb[0];
    float qb1 = fmaf(c.a1, qb0, b * xb[1]);
    float qb2 = fmaf(c.a1, qb1, b * xb[2]);
    float qb3 = fmaf(c.a1, qb2, b * xb[3]);

    float PA = qa3, PB = qb3, u;
    KS_STEP(PA, 1,  c.e0) KS_STEP(PB, 1,  c.e0)
    KS_STEP(PA, 2,  c.e1) KS_STEP(PB, 2,  c.e1)
    KS_STEP(PA, 4,  c.e2) KS_STEP(PB, 4,  c.e2)
    KS_STEP(PA, 8,  c.e3) KS_STEP(PB, 8,  c.e3)
    KS_STEP(PA, 16, c.e4) KS_STEP(PB, 16, c.e4)
    KS_STEP(PA, 32, c.e5) KS_STEP(PB, 32, c.e5)

    float TA = __shfl(PA, 63, 64);
    float TB = __shfl(PB, 63, 64);
    float mB = fmaf(c.a256, m0, TA);
    m0       = fmaf(c.a256, mB, TB);
}

// norm + delta (common prefix of both r-paths)
__device__ __forceinline__ float pcen_norm(float xr, float M, float nalpha, float delta) {
    float m = EPSV + M;
    return fmaf(xr, fast_exp2(nalpha * fast_log2(m)), delta);
}

__global__ __launch_bounds__(256, 8) void pcen_ema_kernel(
    const float* __restrict__ x,
    const float* __restrict__ alpha_p,
    const float* __restrict__ delta_p,
    const float* __restrict__ r_p,
    float* __restrict__ y,
    int rows, int T)
{
    const int gid   = blockIdx.x * blockDim.x + threadIdx.x;
    const int wave  = gid >> 6;
    const int lane  = gid & 63;
    const int row   = wave >> 1;
    const int chunk = wave & 1;
    if (row >= rows) return;

    const float nalpha = -alpha_p[0];
    const float delta  = delta_p[0];
    const float r      = r_p[0];
    const bool  rhalf  = (r == 0.5f);
    const float dr     = rhalf ? __builtin_sqrtf(delta)
                               : fast_exp2(r * fast_log2(delta));

    KC c;
    c.lane = lane;
    const float a = 1.0f - SMOOTH;
    c.a1 = a;  c.a2 = a * a;  c.a3 = c.a2 * a;  c.a4 = c.a2 * c.a2;
    c.e0 = c.a4;        c.e1 = c.e0 * c.e0;  c.e2 = c.e1 * c.e1;
    c.e3 = c.e2 * c.e2; c.e4 = c.e3 * c.e3;  c.e5 = c.e4 * c.e4;
    c.a256 = c.e5 * c.e5;
    float a4l = 1.0f;
    if (lane & 1)  a4l *= c.e0;
    if (lane & 2)  a4l *= c.e1;
    if (lane & 4)  a4l *= c.e2;
    if (lane & 8)  a4l *= c.e3;
    if (lane & 16) a4l *= c.e4;
    if (lane & 32) a4l *= c.e5;
    c.a4lane = a4l;

    const long long base = (long long)row * T;
    const float* __restrict__ xrow = x + base;
    float* __restrict__       yrow = y + base;

    const int tstart = chunk ? HALF : 0;
    const int tend   = chunk ? T    : HALF;   // chunk0: 4096, chunk1: 3904
    const int off    = 4 * lane;

    float m0 = 0.0f;

    // chunk1: 512-step warm-up (no stores)
    if (chunk) {
        const int tw = HALF - WARM;
        v4f wa = *(const v4f*)(xrow + tw + off);
        v4f wb = *(const v4f*)(xrow + tw + 256 + off);
        float xa[4] = { fmaxf(wa.x,0.f), fmaxf(wa.y,0.f), fmaxf(wa.z,0.f), fmaxf(wa.w,0.f) };
        float xb[4] = { fmaxf(wb.x,0.f), fmaxf(wb.y,0.f), fmaxf(wb.z,0.f), fmaxf(wb.w,0.f) };
        scan2(c, xa, xb, m0);
    }

    // main loop: 1024-elem groups (4 tiles); chunk0 has 4 full groups,
    // chunk1 has 3 full + 832-elem remainder handled by clamped loads +
    // predicated stores (invalid positions come after all valid ones).
    const int span  = tend - tstart;
    const int ngrp  = (span + 1023) >> 10;
    int t = tstart;

    v4f v0, v1, v2, v3;
    {
        const int lim = tend - 4;
        int t0 = t + off, t1 = t + 256 + off, t2 = t + 512 + off, t3 = t + 768 + off;
        v0 = *(const v4f*)(xrow + (t0 < lim ? t0 : lim));
        v1 = *(const v4f*)(xrow + (t1 < lim ? t1 : lim));
        v2 = *(const v4f*)(xrow + (t2 < lim ? t2 : lim));
        v3 = *(const v4f*)(xrow + (t3 < lim ? t3 : lim));
    }
    for (int i = 0; i < ngrp; ++i) {
        const int tn = t + 1024;
        // prefetch next group (clamped in-row)
        v4f n0, n1, n2, n3;
        {
            const int tb  = (i + 1 < ngrp) ? tn : t;
            const int lim = tend - 4;
            int t0 = tb + off, t1 = tb + 256 + off, t2 = tb + 512 + off, t3 = tb + 768 + off;
            n0 = *(const v4f*)(xrow + (t0 < lim ? t0 : lim));
            n1 = *(const v4f*)(xrow + (t1 < lim ? t1 : lim));
            n2 = *(const v4f*)(xrow + (t2 < lim ? t2 : lim));
            n3 = *(const v4f*)(xrow + (t3 < lim ? t3 : lim));
        }

        float x0[4] = { fmaxf(v0.x,0.f), fmaxf(v0.y,0.f), fmaxf(v0.z,0.f), fmaxf(v0.w,0.f) };
        float x1[4] = { fmaxf(v1.x,0.f), fmaxf(v1.y,0.f), fmaxf(v1.z,0.f), fmaxf(v1.w,0.f) };
        float x2[4] = { fmaxf(v2.x,0.f), fmaxf(v2.y,0.f), fmaxf(v2.z,0.f), fmaxf(v2.w,0.f) };
        float x3[4] = { fmaxf(v3.x,0.f), fmaxf(v3.y,0.f), fmaxf(v3.z,0.f), fmaxf(v3.w,0.f) };
        float M0[4], M1[4], M2[4], M3[4];
        scan4(c, x0, x1, x2, x3, m0, M0, M1, M2, M3);

        float p0[4], p1[4], p2[4], p3[4];
        #pragma unroll
        for (int k = 0; k < 4; ++k) {
            p0[k] = pcen_norm(x0[k], M0[k], nalpha, delta);
            p1[k] = pcen_norm(x1[k], M1[k], nalpha, delta);
            p2[k] = pcen_norm(x2[k], M2[k], nalpha, delta);
            p3[k] = pcen_norm(x3[k], M3[k], nalpha, delta);
        }

        v4f o0, o1, o2, o3;
        if (rhalf) {     // r == 0.5: single v_sqrt replaces exp2(log2)
            #pragma unroll
            for (int k = 0; k < 4; ++k) {
                ((float*)&o0)[k] = __builtin_sqrtf(p0[k]) - dr;
                ((float*)&o1)[k] = __builtin_sqrtf(p1[k]) - dr;
                ((float*)&o2)[k] = __builtin_sqrtf(p2[k]) - dr;
                ((float*)&o3)[k] = __builtin_sqrtf(p3[k]) - dr;
            }
        } else {
            #pragma unroll
            for (int k = 0; k < 4; ++k) {
                ((float*)&o0)[k] = fast_exp2(r * fast_log2(p0[k])) - dr;
                ((float*)&o1)[k] = fast_exp2(r * fast_log2(p1[k])) - dr;
                ((float*)&o2)[k] = fast_exp2(r * fast_log2(p2[k])) - dr;
                ((float*)&o3)[k] = fast_exp2(r * fast_log2(p3[k])) - dr;
            }
        }
        if (tn <= tend) {   // full group (the common case)
            __builtin_nontemporal_store(o0, (v4f*)(yrow + t + off));
            __builtin_nontemporal_store(o1, (v4f*)(yrow + t + 256 + off));
            __builtin_nontemporal_store(o2, (v4f*)(yrow + t + 512 + off));
            __builtin_nontemporal_store(o3, (v4f*)(yrow + t + 768 + off));
        } else {            // remainder group: predicated 16B stores
            if (t + off       + 4 <= tend) __builtin_nontemporal_store(o0, (v4f*)(yrow + t + off));
            if (t + 256 + off + 4 <= tend) __builtin_nontemporal_store(o1, (v4f*)(yrow + t + 256 + off));
            if (t + 512 + off + 4 <= tend) __builtin_nontemporal_store(o2, (v4f*)(yrow + t + 512 + off));
            if (t + 768 + off + 4 <= tend) __builtin_nontemporal_store(o3, (v4f*)(yrow + t + 768 + off));
        }

        v0 = n0; v1 = n1; v2 = n2; v3 = n3; t = tn;
    }
}

extern "C" void kernel_launch(void* const* d_in, const int* in_sizes, int n_in,
                              void* d_out, int out_size, void* d_ws, size_t ws_size,
                              hipStream_t stream) {
    const float* x     = (const float*)d_in[0];
    const float* alpha = (const float*)d_in[1];
    const float* delta = (const float*)d_in[2];
    const float* r     = (const float*)d_in[3];
    float* y = (float*)d_out;

    const int T     = 8000;
    const int total = in_sizes[0];
    const int rows  = total / T;              // 4096

    const int waves   = rows * 2;             // 2 T-chunks per row
    const int threads = waves * 64;
    const int block   = 256;
    const int grid    = (threads + block - 1) / block;
    pcen_ema_kernel<<<grid, block, 0, stream>>>(x, alpha, delta, r, y, rows, T);
}

// Round 8
// 49.243 us; speedup vs baseline: 1.9157x; 1.9157x over previous
//
#include <hip/hip_runtime.h>

#define EPSV   1e-6f
#define SMOOTH 0.025f
#define HALF   4096      // chunk0 = [0,4096), chunk1 = [4096,T)
#define WARM   512       // EMA warm-up steps for chunk1 (a^512 ~ 2.4e-6)

typedef float v4f __attribute__((ext_vector_type(4)));

__device__ __forceinline__ float fast_log2(float v) { return __builtin_amdgcn_logf(v); }
__device__ __forceinline__ float fast_exp2(float v) { return __builtin_amdgcn_exp2f(v); }

struct KC {
    float a1, a2, a3, a4;            // a^k
    float e0, e1, e2, e3, e4, e5;    // a^(4*2^s)
    float a4lane;                    // a^(4*lane)
    float a256;                      // a^256
    int   lane;
};

#define KS_STEP(P, d, e) \
    u = __shfl_up(P, d, 64); P = fmaf(c.lane >= d ? e : 0.f, u, P);

// 4 interleaved Kogge-Stone chains over 4 coalesced 256-elem tiles
// (lane owns tile_k[4l..4l+3]). 4-way ILP through the 6-step dependent
// shuffle phase; inter-tile carry enters via 4 trailing FMAs only.
__device__ __forceinline__ void scan4(const KC& c,
        const float x0[4], const float x1[4], const float x2[4], const float x3[4],
        float& m0, float M0[4], float M1[4], float M2[4], float M3[4]) {
    const float b = SMOOTH;
    float q00 = b * x0[0];
    float q01 = fmaf(c.a1, q00, b * x0[1]);
    float q02 = fmaf(c.a1, q01, b * x0[2]);
    float q03 = fmaf(c.a1, q02, b * x0[3]);
    float q10 = b * x1[0];
    float q11 = fmaf(c.a1, q10, b * x1[1]);
    float q12 = fmaf(c.a1, q11, b * x1[2]);
    float q13 = fmaf(c.a1, q12, b * x1[3]);
    float q20 = b * x2[0];
    float q21 = fmaf(c.a1, q20, b * x2[1]);
    float q22 = fmaf(c.a1, q21, b * x2[2]);
    float q23 = fmaf(c.a1, q22, b * x2[3]);
    float q30 = b * x3[0];
    float q31 = fmaf(c.a1, q30, b * x3[1]);
    float q32 = fmaf(c.a1, q31, b * x3[2]);
    float q33 = fmaf(c.a1, q32, b * x3[3]);

    float P0 = q03, P1 = q13, P2 = q23, P3 = q33, u;
    KS_STEP(P0, 1,  c.e0) KS_STEP(P1, 1,  c.e0) KS_STEP(P2, 1,  c.e0) KS_STEP(P3, 1,  c.e0)
    KS_STEP(P0, 2,  c.e1) KS_STEP(P1, 2,  c.e1) KS_STEP(P2, 2,  c.e1) KS_STEP(P3, 2,  c.e1)
    KS_STEP(P0, 4,  c.e2) KS_STEP(P1, 4,  c.e2) KS_STEP(P2, 4,  c.e2) KS_STEP(P3, 4,  c.e2)
    KS_STEP(P0, 8,  c.e3) KS_STEP(P1, 8,  c.e3) KS_STEP(P2, 8,  c.e3) KS_STEP(P3, 8,  c.e3)
    KS_STEP(P0, 16, c.e4) KS_STEP(P1, 16, c.e4) KS_STEP(P2, 16, c.e4) KS_STEP(P3, 16, c.e4)
    KS_STEP(P0, 32, c.e5) KS_STEP(P1, 32, c.e5) KS_STEP(P2, 32, c.e5) KS_STEP(P3, 32, c.e5)

    float T0 = __shfl(P0, 63, 64);
    float T1 = __shfl(P1, 63, 64);
    float T2 = __shfl(P2, 63, 64);
    float T3 = __shfl(P3, 63, 64);
    float E0 = __shfl_up(P0, 1, 64); if (c.lane == 0) E0 = 0.f;
    float E1 = __shfl_up(P1, 1, 64); if (c.lane == 0) E1 = 0.f;
    float E2 = __shfl_up(P2, 1, 64); if (c.lane == 0) E2 = 0.f;
    float E3 = __shfl_up(P3, 1, 64); if (c.lane == 0) E3 = 0.f;

    float mA = m0;                       // state entering tile 0
    float mB = fmaf(c.a256, mA, T0);
    float mC = fmaf(c.a256, mB, T1);
    float mD = fmaf(c.a256, mC, T2);
    m0       = fmaf(c.a256, mD, T3);     // carry out

    float s0 = fmaf(c.a4lane, mA, E0);
    float s1 = fmaf(c.a4lane, mB, E1);
    float s2 = fmaf(c.a4lane, mC, E2);
    float s3 = fmaf(c.a4lane, mD, E3);
    M0[0] = fmaf(c.a1, s0, q00); M0[1] = fmaf(c.a2, s0, q01);
    M0[2] = fmaf(c.a3, s0, q02); M0[3] = fmaf(c.a4, s0, q03);
    M1[0] = fmaf(c.a1, s1, q10); M1[1] = fmaf(c.a2, s1, q11);
    M1[2] = fmaf(c.a3, s1, q12); M1[3] = fmaf(c.a4, s1, q13);
    M2[0] = fmaf(c.a1, s2, q20); M2[1] = fmaf(c.a2, s2, q21);
    M2[2] = fmaf(c.a3, s2, q22); M2[3] = fmaf(c.a4, s2, q23);
    M3[0] = fmaf(c.a1, s3, q30); M3[1] = fmaf(c.a2, s3, q31);
    M3[2] = fmaf(c.a3, s3, q32); M3[3] = fmaf(c.a4, s3, q33);
}

// 2-tile variant (warm-up only, carry out only)
__device__ __forceinline__ void scan2(const KC& c,
        const float xa[4], const float xb[4], float& m0) {
    const float b = SMOOTH;
    float qa0 = b * xa[0];
    float qa1 = fmaf(c.a1, qa0, b * xa[1]);
    float qa2 = fmaf(c.a1, qa1, b * xa[2]);
    float qa3 = fmaf(c.a1, qa2, b * xa[3]);
    float qb0 = b * xb[0];
    float qb1 = fmaf(c.a1, qb0, b * xb[1]);
    float qb2 = fmaf(c.a1, qb1, b * xb[2]);
    float qb3 = fmaf(c.a1, qb2, b * xb[3]);

    float PA = qa3, PB = qb3, u;
    KS_STEP(PA, 1,  c.e0) KS_STEP(PB, 1,  c.e0)
    KS_STEP(PA, 2,  c.e1) KS_STEP(PB, 2,  c.e1)
    KS_STEP(PA, 4,  c.e2) KS_STEP(PB, 4,  c.e2)
    KS_STEP(PA, 8,  c.e3) KS_STEP(PB, 8,  c.e3)
    KS_STEP(PA, 16, c.e4) KS_STEP(PB, 16, c.e4)
    KS_STEP(PA, 32, c.e5) KS_STEP(PB, 32, c.e5)

    float TA = __shfl(PA, 63, 64);
    float TB = __shfl(PB, 63, 64);
    float mB = fmaf(c.a256, m0, TA);
    m0       = fmaf(c.a256, mB, TB);
}

// norm + delta (common prefix of both r-paths)
__device__ __forceinline__ float pcen_norm(float xr, float M, float nalpha, float delta) {
    float m = EPSV + M;
    return fmaf(xr, fast_exp2(nalpha * fast_log2(m)), delta);
}

__global__ __launch_bounds__(256, 4) void pcen_ema_kernel(
    const float* __restrict__ x,
    const float* __restrict__ alpha_p,
    const float* __restrict__ delta_p,
    const float* __restrict__ r_p,
    float* __restrict__ y,
    int rows, int T)
{
    const int gid   = blockIdx.x * blockDim.x + threadIdx.x;
    const int wave  = gid >> 6;
    const int lane  = gid & 63;
    const int row   = wave >> 1;
    const int chunk = wave & 1;
    if (row >= rows) return;

    const float nalpha = -alpha_p[0];
    const float delta  = delta_p[0];
    const float r      = r_p[0];
    const bool  rhalf  = (r == 0.5f);
    const float dr     = rhalf ? __builtin_sqrtf(delta)
                               : fast_exp2(r * fast_log2(delta));

    KC c;
    c.lane = lane;
    const float a = 1.0f - SMOOTH;
    c.a1 = a;  c.a2 = a * a;  c.a3 = c.a2 * a;  c.a4 = c.a2 * c.a2;
    c.e0 = c.a4;        c.e1 = c.e0 * c.e0;  c.e2 = c.e1 * c.e1;
    c.e3 = c.e2 * c.e2; c.e4 = c.e3 * c.e3;  c.e5 = c.e4 * c.e4;
    c.a256 = c.e5 * c.e5;
    float a4l = 1.0f;
    if (lane & 1)  a4l *= c.e0;
    if (lane & 2)  a4l *= c.e1;
    if (lane & 4)  a4l *= c.e2;
    if (lane & 8)  a4l *= c.e3;
    if (lane & 16) a4l *= c.e4;
    if (lane & 32) a4l *= c.e5;
    c.a4lane = a4l;

    const long long base = (long long)row * T;
    const float* __restrict__ xrow = x + base;
    float* __restrict__       yrow = y + base;

    const int tstart = chunk ? HALF : 0;
    const int tend   = chunk ? T    : HALF;   // chunk0: 4096, chunk1: 8000
    const int off    = 4 * lane;
    const int lim    = tend - 4;              // clamp for remainder loads

    float m0 = 0.0f;

    // chunk1: 512-step warm-up (no stores)
    if (chunk) {
        const int tw = HALF - WARM;
        v4f wa = *(const v4f*)(xrow + tw + off);
        v4f wb = *(const v4f*)(xrow + tw + 256 + off);
        float xa[4] = { fmaxf(wa.x,0.f), fmaxf(wa.y,0.f), fmaxf(wa.z,0.f), fmaxf(wa.w,0.f) };
        float xb[4] = { fmaxf(wb.x,0.f), fmaxf(wb.y,0.f), fmaxf(wb.z,0.f), fmaxf(wb.w,0.f) };
        scan2(c, xa, xb, m0);
    }

    // main loop: 1024-elem groups (4 coalesced 256-elem tiles).
    // chunk0: 4 full groups. chunk1: 3 full + 832-elem remainder
    // (clamped loads; invalid scan positions come after all stored ones).
    const int ngrp = ((tend - tstart) + 1023) >> 10;
    int t = tstart;

    v4f v0, v1, v2, v3;
    {
        int t0 = t + off, t1 = t + 256 + off, t2 = t + 512 + off, t3 = t + 768 + off;
        v0 = *(const v4f*)(xrow + (t0 < lim ? t0 : lim));
        v1 = *(const v4f*)(xrow + (t1 < lim ? t1 : lim));
        v2 = *(const v4f*)(xrow + (t2 < lim ? t2 : lim));
        v3 = *(const v4f*)(xrow + (t3 < lim ? t3 : lim));
    }
    for (int i = 0; i < ngrp; ++i) {
        const int tn = t + 1024;
        v4f n0 = v0, n1 = v1, n2 = v2, n3 = v3;
        if (i + 1 < ngrp) {            // wave-uniform prefetch guard
            int t0 = tn + off, t1 = tn + 256 + off, t2 = tn + 512 + off, t3 = tn + 768 + off;
            n0 = *(const v4f*)(xrow + (t0 < lim ? t0 : lim));
            n1 = *(const v4f*)(xrow + (t1 < lim ? t1 : lim));
            n2 = *(const v4f*)(xrow + (t2 < lim ? t2 : lim));
            n3 = *(const v4f*)(xrow + (t3 < lim ? t3 : lim));
        }

        float x0[4] = { fmaxf(v0.x,0.f), fmaxf(v0.y,0.f), fmaxf(v0.z,0.f), fmaxf(v0.w,0.f) };
        float x1[4] = { fmaxf(v1.x,0.f), fmaxf(v1.y,0.f), fmaxf(v1.z,0.f), fmaxf(v1.w,0.f) };
        float x2[4] = { fmaxf(v2.x,0.f), fmaxf(v2.y,0.f), fmaxf(v2.z,0.f), fmaxf(v2.w,0.f) };
        float x3[4] = { fmaxf(v3.x,0.f), fmaxf(v3.y,0.f), fmaxf(v3.z,0.f), fmaxf(v3.w,0.f) };
        float M0[4], M1[4], M2[4], M3[4];
        scan4(c, x0, x1, x2, x3, m0, M0, M1, M2, M3);

        float p00 = pcen_norm(x0[0], M0[0], nalpha, delta);
        float p01 = pcen_norm(x0[1], M0[1], nalpha, delta);
        float p02 = pcen_norm(x0[2], M0[2], nalpha, delta);
        float p03 = pcen_norm(x0[3], M0[3], nalpha, delta);
        float p10 = pcen_norm(x1[0], M1[0], nalpha, delta);
        float p11 = pcen_norm(x1[1], M1[1], nalpha, delta);
        float p12 = pcen_norm(x1[2], M1[2], nalpha, delta);
        float p13 = pcen_norm(x1[3], M1[3], nalpha, delta);
        float p20 = pcen_norm(x2[0], M2[0], nalpha, delta);
        float p21 = pcen_norm(x2[1], M2[1], nalpha, delta);
        float p22 = pcen_norm(x2[2], M2[2], nalpha, delta);
        float p23 = pcen_norm(x2[3], M2[3], nalpha, delta);
        float p30 = pcen_norm(x3[0], M3[0], nalpha, delta);
        float p31 = pcen_norm(x3[1], M3[1], nalpha, delta);
        float p32 = pcen_norm(x3[2], M3[2], nalpha, delta);
        float p33 = pcen_norm(x3[3], M3[3], nalpha, delta);

        v4f o0, o1, o2, o3;
        if (rhalf) {     // r == 0.5: single v_sqrt replaces exp2(log2)
            o0.x = __builtin_sqrtf(p00) - dr; o0.y = __builtin_sqrtf(p01) - dr;
            o0.z = __builtin_sqrtf(p02) - dr; o0.w = __builtin_sqrtf(p03) - dr;
            o1.x = __builtin_sqrtf(p10) - dr; o1.y = __builtin_sqrtf(p11) - dr;
            o1.z = __builtin_sqrtf(p12) - dr; o1.w = __builtin_sqrtf(p13) - dr;
            o2.x = __builtin_sqrtf(p20) - dr; o2.y = __builtin_sqrtf(p21) - dr;
            o2.z = __builtin_sqrtf(p22) - dr; o2.w = __builtin_sqrtf(p23) - dr;
            o3.x = __builtin_sqrtf(p30) - dr; o3.y = __builtin_sqrtf(p31) - dr;
            o3.z = __builtin_sqrtf(p32) - dr; o3.w = __builtin_sqrtf(p33) - dr;
        } else {
            o0.x = fast_exp2(r * fast_log2(p00)) - dr; o0.y = fast_exp2(r * fast_log2(p01)) - dr;
            o0.z = fast_exp2(r * fast_log2(p02)) - dr; o0.w = fast_exp2(r * fast_log2(p03)) - dr;
            o1.x = fast_exp2(r * fast_log2(p10)) - dr; o1.y = fast_exp2(r * fast_log2(p11)) - dr;
            o1.z = fast_exp2(r * fast_log2(p12)) - dr; o1.w = fast_exp2(r * fast_log2(p13)) - dr;
            o2.x = fast_exp2(r * fast_log2(p20)) - dr; o2.y = fast_exp2(r * fast_log2(p21)) - dr;
            o2.z = fast_exp2(r * fast_log2(p22)) - dr; o2.w = fast_exp2(r * fast_log2(p23)) - dr;
            o3.x = fast_exp2(r * fast_log2(p30)) - dr; o3.y = fast_exp2(r * fast_log2(p31)) - dr;
            o3.z = fast_exp2(r * fast_log2(p32)) - dr; o3.w = fast_exp2(r * fast_log2(p33)) - dr;
        }

        if (tn <= tend) {   // full group (the common case)
            __builtin_nontemporal_store(o0, (v4f*)(yrow + t + off));
            __builtin_nontemporal_store(o1, (v4f*)(yrow + t + 256 + off));
            __builtin_nontemporal_store(o2, (v4f*)(yrow + t + 512 + off));
            __builtin_nontemporal_store(o3, (v4f*)(yrow + t + 768 + off));
        } else {            // remainder group: predicated 16B stores
            if (t + off       + 4 <= tend) __builtin_nontemporal_store(o0, (v4f*)(yrow + t + off));
            if (t + 256 + off + 4 <= tend) __builtin_nontemporal_store(o1, (v4f*)(yrow + t + 256 + off));
            if (t + 512 + off + 4 <= tend) __builtin_nontemporal_store(o2, (v4f*)(yrow + t + 512 + off));
            if (t + 768 + off + 4 <= tend) __builtin_nontemporal_store(o3, (v4f*)(yrow + t + 768 + off));
        }

        v0 = n0; v1 = n1; v2 = n2; v3 = n3; t = tn;
    }
}

extern "C" void kernel_launch(void* const* d_in, const int* in_sizes, int n_in,
                              void* d_out, int out_size, void* d_ws, size_t ws_size,
                              hipStream_t stream) {
    const float* x     = (const float*)d_in[0];
    const float* alpha = (const float*)d_in[1];
    const float* delta = (const float*)d_in[2];
    const float* r     = (const float*)d_in[3];
    float* y = (float*)d_out;

    const int T     = 8000;
    const int total = in_sizes[0];
    const int rows  = total / T;              // 4096

    const int waves   = rows * 2;             // 2 T-chunks per row
    const int threads = waves * 64;
    const int block   = 256;
    const int grid    = (threads + block - 1) / block;
    pcen_ema_kernel<<<grid, block, 0, stream>>>(x, alpha, delta, r, y, rows, T);
}